// Round 7
// baseline (148.976 us; speedup 1.0000x reference)
//
#include <hip/hip_runtime.h>

#define Wd 640
#define Hd 512
#define NB 32
#define TW 64
#define TH2 32
#define RR 4
#define SW 72
#define ROWS (TH2 + RR)            // 36 staged rows
constexpr int TILES_X = Wd / TW;   // 10
constexpr int TILES_Y = Hd / TH2;  // 16
constexpr int NBLK = TILES_X * TILES_Y * NB;   // 5120
constexpr float EPSC = 0.5f;

// ---------------- census numerator/denominator (d-form, no divide) ----------------
// c(x)=x/(eps+|x|);  ca-cb = (da*d2 - db*d1)/(d1*d2),  d1=eps+|da|, d2=eps+|db|
__device__ __forceinline__ void census_ne(float na, float nb, float ac, float bc,
                                          float& n, float& e)
{
    float da = na - ac;
    float db = nb - bc;
    float d1 = EPSC + fabsf(da);
    float d2 = EPSC + fabsf(db);
    n = fmaf(da, d2, -(db * d1));
    e = d1 * d2;                        // in [0.25, 2.25]
}

// Sum of 4 terms with ONE rcp
__device__ __forceinline__ float comb4(float n1, float e1, float n2, float e2,
                                       float n3, float e3, float n4, float e4)
{
    float e12 = e1 * e2, e34 = e3 * e4;
    float s12 = fmaf(fabsf(n2), e1, fabsf(n1) * e2);
    float s34 = fmaf(fabsf(n4), e3, fabsf(n3) * e4);
    float t   = fmaf(s34, e12, s12 * e34);
    return t * __builtin_amdgcn_rcpf(e12 * e34);
}

// full 9-wide row terms for pixel J (window cols J..J+8, center wa[J+4]==ca[J])
#define PX_ROW(J, ACC) { \
    float n0,e0,n1,e1,n2,e2,n3,e3,n4,e4,n5,e5,n6,e6,n7,e7,n8,e8; \
    census_ne(wa[(J)+0],wb[(J)+0],ca[J],cb[J],n0,e0); \
    census_ne(wa[(J)+1],wb[(J)+1],ca[J],cb[J],n1,e1); \
    census_ne(wa[(J)+2],wb[(J)+2],ca[J],cb[J],n2,e2); \
    census_ne(wa[(J)+3],wb[(J)+3],ca[J],cb[J],n3,e3); \
    census_ne(wa[(J)+4],wb[(J)+4],ca[J],cb[J],n4,e4); \
    census_ne(wa[(J)+5],wb[(J)+5],ca[J],cb[J],n5,e5); \
    census_ne(wa[(J)+6],wb[(J)+6],ca[J],cb[J],n6,e6); \
    census_ne(wa[(J)+7],wb[(J)+7],ca[J],cb[J],n7,e7); \
    census_ne(wa[(J)+8],wb[(J)+8],ca[J],cb[J],n8,e8); \
    if constexpr (EC) { n0*=m[(J)+0]; n1*=m[(J)+1]; n2*=m[(J)+2]; n3*=m[(J)+3]; \
                        n5*=m[(J)+5]; n6*=m[(J)+6]; n7*=m[(J)+7]; n8*=m[(J)+8]; } \
    if constexpr (ER) { n0*=mv; n1*=mv; n2*=mv; n3*=mv; n4*=mv; \
                        n5*=mv; n6*=mv; n7*=mv; n8*=mv; } \
    ACC += comb4(n0,e0,n1,e1,n2,e2,n3,e3); \
    ACC += comb4(n5,e5,n6,e6,n7,e7,n8,e8); \
    ACC = fmaf(fabsf(n4), __builtin_amdgcn_rcpf(e4), ACC); }

// center row of pixel J: right-half terms d=1..4 (window cols J+5..J+8)
#define PX_CTR(J, ACC) { \
    float n0,e0,n1,e1,n2,e2,n3,e3; \
    census_ne(wa[(J)+5],wb[(J)+5],ca[J],cb[J],n0,e0); \
    census_ne(wa[(J)+6],wb[(J)+6],ca[J],cb[J],n1,e1); \
    census_ne(wa[(J)+7],wb[(J)+7],ca[J],cb[J],n2,e2); \
    census_ne(wa[(J)+8],wb[(J)+8],ca[J],cb[J],n3,e3); \
    if constexpr (EC) { n0*=m[(J)+5]; n1*=m[(J)+6]; n2*=m[(J)+7]; n3*=m[(J)+8]; } \
    ACC += comb4(n0,e0,n1,e1,n2,e2,n3,e3); }

template<bool EC, bool ER>
__device__ __forceinline__ float strip_sum(const float (*sa)[SW], const float (*sb)[SW],
                                           int ty, int tx, int ub, int v0)
{
    float m[12];
    if constexpr (EC) {
        #pragma unroll
        for (int i = 0; i < 12; ++i)
            m[i] = ((unsigned)(ub + i - 4) < (unsigned)Wd) ? 1.f : 0.f;
    }
    const int cu = 4 * tx;
    float acc0 = 0.f, acc1 = 0.f, acc2 = 0.f, acc3 = 0.f;

    for (int rb = ty; rb < TH2; rb += 16) {         // 2 strips of 4 px per thread
        float ca[4], cb[4], wa[12], wb[12];
        {   // center row: cols cu+4 .. cu+11
            float4 A1 = *(const float4*)&sa[rb][cu + 4];
            float4 A2 = *(const float4*)&sa[rb][cu + 8];
            float4 B1 = *(const float4*)&sb[rb][cu + 4];
            float4 B2 = *(const float4*)&sb[rb][cu + 8];
            wa[4]=A1.x; wa[5]=A1.y; wa[6]=A1.z; wa[7]=A1.w;
            wa[8]=A2.x; wa[9]=A2.y; wa[10]=A2.z; wa[11]=A2.w;
            wb[4]=B1.x; wb[5]=B1.y; wb[6]=B1.z; wb[7]=B1.w;
            wb[8]=B2.x; wb[9]=B2.y; wb[10]=B2.z; wb[11]=B2.w;
            ca[0]=wa[4]; ca[1]=wa[5]; ca[2]=wa[6]; ca[3]=wa[7];
            cb[0]=wb[4]; cb[1]=wb[5]; cb[2]=wb[6]; cb[3]=wb[7];
            PX_CTR(0, acc0) PX_CTR(1, acc1) PX_CTR(2, acc2) PX_CTR(3, acc3)
        }
        for (int dh = 1; dh <= RR; ++dh) {          // rolled: only LDS addresses vary
            float wa[12], wb[12];
            float4 A0 = *(const float4*)&sa[rb + dh][cu];
            float4 A1 = *(const float4*)&sa[rb + dh][cu + 4];
            float4 A2 = *(const float4*)&sa[rb + dh][cu + 8];
            float4 B0 = *(const float4*)&sb[rb + dh][cu];
            float4 B1 = *(const float4*)&sb[rb + dh][cu + 4];
            float4 B2 = *(const float4*)&sb[rb + dh][cu + 8];
            wa[0]=A0.x; wa[1]=A0.y; wa[2]=A0.z; wa[3]=A0.w;
            wa[4]=A1.x; wa[5]=A1.y; wa[6]=A1.z; wa[7]=A1.w;
            wa[8]=A2.x; wa[9]=A2.y; wa[10]=A2.z; wa[11]=A2.w;
            wb[0]=B0.x; wb[1]=B0.y; wb[2]=B0.z; wb[3]=B0.w;
            wb[4]=B1.x; wb[5]=B1.y; wb[6]=B1.z; wb[7]=B1.w;
            wb[8]=B2.x; wb[9]=B2.y; wb[10]=B2.z; wb[11]=B2.w;
            float mv = 0.f;
            if constexpr (ER) mv = (v0 + rb + dh < Hd) ? 1.f : 0.f;
            (void)mv;
            PX_ROW(0, acc0) PX_ROW(1, acc1) PX_ROW(2, acc2) PX_ROW(3, acc3)
        }
    }
    return (acc0 + acc1) + (acc2 + acc3);
}

// ------------- fused kernel: warp-into-LDS staging + census over 64x32 tiles -------------
__global__ __launch_bounds__(256)
void fused_census(const float* __restrict__ disp, const float* __restrict__ im,
                  const float* __restrict__ pattern, float* __restrict__ proj,
                  float* __restrict__ partial)
{
    __shared__ float sa[ROWS][SW];   // warped pattern (proj), rows v0..v0+35
    __shared__ float sb[ROWS][SW];   // im

    const int tU = blockIdx.x, tV = blockIdx.y, b = blockIdx.z;
    const int tid = threadIdx.x;
    const size_t HW = (size_t)Hd * Wd;
    const float* dsp = disp + (size_t)b * HW;
    const float* ib  = im   + (size_t)b * HW;
    float* pj        = proj + (size_t)b * HW;
    const int v0  = tV * TH2;
    const int u0g = tU * TW - RR;               // global col of LDS col 0

    const bool edgeC = (tU == 0) | (tU == TILES_X - 1);
    const bool edgeR = (tV == TILES_Y - 1);

    if (!edgeC && !edgeR) {
        // fast staging: all addresses in-bounds; float4 loads (u0g % 4 == 0)
        for (int f = tid; f < ROWS * 18; f += 256) {
            int r  = f / 18;
            int c4 = (f - 18 * r) * 4;
            int gy = v0 + r;
            int gx = u0g + c4;
            const float* prow = pattern + (size_t)gy * Wd;
            float4 dv = *(const float4*)(dsp + (size_t)gy * Wd + gx);
            float4 iv = *(const float4*)(ib  + (size_t)gy * Wd + gx);
            *(float4*)&sb[r][c4] = iv;
            float pv[4];
            float dd[4] = {dv.x, dv.y, dv.z, dv.w};
            #pragma unroll
            for (int k = 0; k < 4; ++k) {
                float x = (float)(gx + k) - dd[k];
                x = fminf(fmaxf(x, 0.f), (float)(Wd - 1));
                float x0 = floorf(x);
                float w  = x - x0;
                int i0 = (int)x0;
                int i1 = min(i0 + 1, Wd - 1);
                float g0 = prow[i0];
                float g1 = prow[i1];
                pv[k] = fmaf(w, g1 - g0, g0);
            }
            float4 pq = {pv[0], pv[1], pv[2], pv[3]};
            *(float4*)&sa[r][c4] = pq;
            if (r < TH2 && c4 >= RR && c4 <= RR + TW - 4) {   // owned interior cols
                float* dst = pj + (size_t)gy * Wd + gx;        // d_out+1: scalar stores
                dst[0] = pv[0]; dst[1] = pv[1]; dst[2] = pv[2]; dst[3] = pv[3];
            }
        }
    } else {
        for (int idx = tid; idx < ROWS * SW; idx += 256) {
            int r = idx / SW;
            int c = idx - r * SW;
            int gv = min(v0 + r, Hd - 1);
            int gu = min(max(u0g + c, 0), Wd - 1);
            size_t off = (size_t)gv * Wd + gu;
            sb[r][c] = ib[off];
            float d = dsp[off];
            float x = (float)gu - d;
            x = fminf(fmaxf(x, 0.f), (float)(Wd - 1));
            float x0 = floorf(x);
            float w  = x - x0;
            int i0 = (int)x0;
            int i1 = min(i0 + 1, Wd - 1);
            const float* prow = pattern + (size_t)gv * Wd;
            float val = fmaf(w, prow[i1] - prow[i0], prow[i0]);
            sa[r][c] = val;
            if (r < TH2 && c >= RR && c < RR + TW)            // owned px (always in-bounds)
                pj[(size_t)(v0 + r) * Wd + (u0g + c)] = val;
        }
    }
    __syncthreads();

    const int ty = tid >> 4;                    // 0..15
    const int tx = tid & 15;                    // 0..15
    const int ub = tU * TW + 4 * tx;            // global col of px 0

    float acc;
    if (!edgeC && !edgeR)      acc = strip_sum<false, false>(sa, sb, ty, tx, ub, v0);
    else if (edgeC && !edgeR)  acc = strip_sum<true,  false>(sa, sb, ty, tx, ub, v0);
    else if (!edgeC)           acc = strip_sum<false, true >(sa, sb, ty, tx, ub, v0);
    else                       acc = strip_sum<true,  true >(sa, sb, ty, tx, ub, v0);

    // block reduction -> one partial per block (deterministic)
    #pragma unroll
    for (int o = 32; o; o >>= 1) acc += __shfl_down(acc, o);
    __shared__ float wsum[4];
    int wid = tid >> 6, lane = tid & 63;
    if (lane == 0) wsum[wid] = acc;
    __syncthreads();
    if (tid == 0) {
        float s = wsum[0] + wsum[1] + wsum[2] + wsum[3];
        partial[((int)blockIdx.z * gridDim.y + blockIdx.y) * gridDim.x + blockIdx.x] = s;
    }
}

// ---------------- final deterministic reduce ----------------
__global__ __launch_bounds__(1024)
void final_reduce(const float* __restrict__ partial, float* __restrict__ out)
{
    double s = 0.0;
    for (int i = threadIdx.x; i < NBLK; i += 1024) s += (double)partial[i];
    __shared__ double sm[1024];
    sm[threadIdx.x] = s;
    __syncthreads();
    for (int st = 512; st; st >>= 1) {
        if (threadIdx.x < st) sm[threadIdx.x] += sm[threadIdx.x + st];
        __syncthreads();
    }
    if (threadIdx.x == 0) {
        // val = 2 * S_half / (81 * B*H*W)   (half-space symmetry doubling)
        out[0] = (float)(sm[0] * (2.0 / (81.0 * (double)NB * Hd * Wd)));
    }
}

extern "C" void kernel_launch(void* const* d_in, const int* in_sizes, int n_in,
                              void* d_out, int out_size, void* d_ws, size_t ws_size,
                              hipStream_t stream)
{
    const float* disp    = (const float*)d_in[0];
    const float* im      = (const float*)d_in[1];
    const float* pattern = (const float*)d_in[2];
    float* out  = (float*)d_out;
    float* proj = out + 1;                      // output 1: pattern_proj
    float* partial = (float*)d_ws;              // 5120 floats scratch

    dim3 grid(TILES_X, TILES_Y, NB);
    fused_census<<<grid, 256, 0, stream>>>(disp, im, pattern, proj, partial);
    final_reduce<<<1, 1024, 0, stream>>>(partial, out);
}